// Round 3
// baseline (287.943 us; speedup 1.0000x reference)
//
#include <hip/hip_runtime.h>

// Problem constants (from reference): N=50000, E=625000, D=128.
constexpr int D = 128;
constexpr int CAP = 64;   // per-node bucket capacity

// DIAGNOSTIC ROUND 2: measure prep and both GEMMs by repeating their full
// bodies enough times to cross the rocprof top-5 cutoff (~44us, set by the
// harness re-poison fills). All repeats are idempotent (identical bytes
// re-stored each pass; per-pass stores keep every pass live vs DCE).
//   true prep cost  = prep_row_dur / PREP_REPEATS
//   true gemm cost  = gemm_row_dur / GEMM_REPEATS
// Checksum: dur_us - 210 == 5*prep + 6*(gemm1+gemm2).
// Gathers are back to x1 (measured ~15us each in round 1's ablation).
constexpr int PREP_REPEATS = 6;
constexpr int GEMM_REPEATS = 7;

using short8 = __attribute__((ext_vector_type(8))) short;
using f32x4  = __attribute__((ext_vector_type(4))) float;

// RNE float -> bf16 (finite inputs).
__device__ inline unsigned short f2bf(float f) {
    union { float f; unsigned u; } un;
    un.f = f;
    unsigned u = un.u;
    return (unsigned short)((u + 0x7fffu + ((u >> 16) & 1u)) >> 16);
}

// ===========================================================================
// Fused prep (1 dispatch): zero counters | fp32->bf16 x | both bswz blocks.
// DIAGNOSTIC: whole body repeated PREP_REPEATS times (idempotent).
// ===========================================================================
__global__ __launch_bounds__(256) void prep_kernel(
    const float* __restrict__ x,
    const float* __restrict__ W1_rel, const float* __restrict__ W1_root,
    const float* __restrict__ W2_rel, const float* __restrict__ W2_root,
    unsigned short* __restrict__ xb,
    unsigned short* __restrict__ bswz1, unsigned short* __restrict__ bswz2,
    int* __restrict__ cnt, int n, int feat4) {
    const int gtid = blockIdx.x * blockDim.x + threadIdx.x;
    const int gsz = gridDim.x * blockDim.x;

#pragma unroll 1
    for (int rep = 0; rep < PREP_REPEATS; ++rep) {
        for (int i = gtid; i < n; i += gsz) cnt[i] = 0;  // ws is 0xAA-poisoned
        for (int i = gtid; i < feat4; i += gsz) {
            float4 v = reinterpret_cast<const float4*>(x)[i];
            unsigned short o[4] = {f2bf(v.x), f2bf(v.y), f2bf(v.z), f2bf(v.w)};
            reinterpret_cast<uint2*>(xb)[i] = *reinterpret_cast<uint2*>(o);
        }
        for (int idx = gtid; idx < 2 * 4096; idx += gsz) {
            const int which = idx >> 12;          // 0: layer1, 1: layer2
            const int id = idx & 4095;
            const int lane = id & 63;
            const int t = (id >> 6) & 7;
            const int qq = id >> 9;
            const float* W = (qq < 4) ? (which ? W2_rel : W1_rel)
                                      : (which ? W2_root : W1_root);
            const int col = t * 16 + (lane & 15);
            const int kbase = (qq & 3) * 32 + ((lane >> 4) * 8);
            unsigned short o[8];
#pragma unroll
            for (int j = 0; j < 8; ++j)
                o[j] = f2bf(W[(size_t)(kbase + j) * D + col]);
            uint4* dp = reinterpret_cast<uint4*>((which ? bswz2 : bswz1) +
                                                 (size_t)id * 8);
            *dp = *reinterpret_cast<uint4*>(o);
        }
    }
}

// ===========================================================================
// Bucket-append adjacency build, 4 edges/thread via int4. UNCHANGED
// (measured ~45us via its own top-5 row; reference point this round).
// ===========================================================================
__global__ void build_buckets_kernel(const int* __restrict__ src,
                                     const int* __restrict__ dst,
                                     int* __restrict__ cnt,
                                     int* __restrict__ esrc, int E) {
    const int t = blockIdx.x * blockDim.x + threadIdx.x;
    const int base = t * 4;
    if (base + 3 < E) {
        const int4 s4 = *reinterpret_cast<const int4*>(src + base);
        const int4 d4 = *reinterpret_cast<const int4*>(dst + base);
        int p;
        p = atomicAdd(&cnt[d4.x], 1); if (p < CAP) esrc[d4.x * CAP + p] = s4.x;
        p = atomicAdd(&cnt[d4.y], 1); if (p < CAP) esrc[d4.y * CAP + p] = s4.y;
        p = atomicAdd(&cnt[d4.z], 1); if (p < CAP) esrc[d4.z * CAP + p] = s4.z;
        p = atomicAdd(&cnt[d4.w], 1); if (p < CAP) esrc[d4.w * CAP + p] = s4.w;
    } else if (base < E) {
        for (int i = base; i < E; ++i) {
            const int d = dst[i];
            const int p = atomicAdd(&cnt[d], 1);
            if (p < CAP) esrc[d * CAP + p] = src[i];
        }
    }
}

// ===========================================================================
// bf16 gather-accumulate, 16-deep MLP version (back to x1; ~15us measured).
// ===========================================================================
__device__ inline void add8(float* acc, uint4 v) {
    const unsigned u0 = v.x, u1 = v.y, u2 = v.z, u3 = v.w;
    acc[0] += __uint_as_float(u0 << 16);
    acc[1] += __uint_as_float(u0 & 0xffff0000u);
    acc[2] += __uint_as_float(u1 << 16);
    acc[3] += __uint_as_float(u1 & 0xffff0000u);
    acc[4] += __uint_as_float(u2 << 16);
    acc[5] += __uint_as_float(u2 & 0xffff0000u);
    acc[6] += __uint_as_float(u3 << 16);
    acc[7] += __uint_as_float(u3 & 0xffff0000u);
}

__global__ __launch_bounds__(256) void gather_bf16_kernel(
    const unsigned short* __restrict__ xb,
    const int* __restrict__ cnt,
    const int* __restrict__ esrc,
    unsigned short* __restrict__ aggb, int n) {
    const int tid = blockIdx.x * blockDim.x + threadIdx.x;
    const int g = tid >> 4;
    const int lane = tid & 15;
    if (g >= n) return;
    int deg = cnt[g];
    deg = (deg < CAP) ? deg : CAP;
    const int beg = g * CAP;
    const size_t loff = (size_t)lane * 8;
    float acc[8] = {0.f, 0.f, 0.f, 0.f, 0.f, 0.f, 0.f, 0.f};

    for (int j0 = 0; j0 < deg; j0 += 16) {
        const int rem = deg - j0;
        const int4 ia = *reinterpret_cast<const int4*>(esrc + beg + j0 + 0);
        const int4 ib = *reinterpret_cast<const int4*>(esrc + beg + j0 + 4);
        const int4 ic = *reinterpret_cast<const int4*>(esrc + beg + j0 + 8);
        const int4 id = *reinterpret_cast<const int4*>(esrc + beg + j0 + 12);
        const int s[16] = {ia.x, ia.y, ia.z, ia.w, ib.x, ib.y, ib.z, ib.w,
                           ic.x, ic.y, ic.z, ic.w, id.x, id.y, id.z, id.w};
        uint4 v[16];
#pragma unroll
        for (int k = 0; k < 16; ++k) {
            const int sk = (k < rem) ? s[k] : 0;
            v[k] = *reinterpret_cast<const uint4*>(xb + (size_t)sk * D + loff);
        }
#pragma unroll
        for (int k = 0; k < 16; ++k) {
            if (k < rem) add8(acc, v[k]);
        }
    }

    unsigned short o[8];
#pragma unroll
    for (int i = 0; i < 8; ++i) o[i] = f2bf(acc[i]);
    *reinterpret_cast<uint4*>(aggb + (size_t)g * D + lane * 8) =
        *reinterpret_cast<uint4*>(o);
}

// ===========================================================================
// MFMA GEMM: out[i,:] = (relu?)( Ab[i,:] @ Wrel + bias + Xb[i,:] @ Wroot )
// K = 256, bf16 inputs, fp32 acc. Block = 4 waves; wave = 32 rows x 128 cols.
// DIAGNOSTIC: whole body repeated GEMM_REPEATS times (idempotent; acc
// re-zeroed and output re-stored each pass).
// ===========================================================================
template <bool RELU, bool OUT_BF16>
__global__ __launch_bounds__(256) void mfma_gemm_kernel(
    const unsigned short* __restrict__ Ab, const unsigned short* __restrict__ Xb,
    const unsigned short* __restrict__ Bswz, const float* __restrict__ bias,
    unsigned short* __restrict__ outb, float* __restrict__ outf, int n) {
    const int t = threadIdx.x;
    const int lane = t & 63;
    const int w = t >> 6;
    const int quad = lane >> 4;
    const int l15 = lane & 15;
    const int R0 = blockIdx.x * 128 + w * 32;

    int rowA0 = R0 + l15;
    int rowA1 = R0 + 16 + l15;
    rowA0 = (rowA0 < n) ? rowA0 : (n - 1);
    rowA1 = (rowA1 < n) ? rowA1 : (n - 1);

#pragma unroll 1
    for (int rep = 0; rep < GEMM_REPEATS; ++rep) {
        f32x4 acc[2][8];
#pragma unroll
        for (int rt = 0; rt < 2; ++rt)
#pragma unroll
            for (int nt = 0; nt < 8; ++nt)
                acc[rt][nt] = f32x4{0.f, 0.f, 0.f, 0.f};

        for (int qq = 0; qq < 8; ++qq) {
            const unsigned short* Asrc = (qq < 4) ? Ab : Xb;
            const int kb = (qq & 3) * 32 + quad * 8;
            short8 a0 = *reinterpret_cast<const short8*>(Asrc + (size_t)rowA0 * D + kb);
            short8 a1 = *reinterpret_cast<const short8*>(Asrc + (size_t)rowA1 * D + kb);
            const unsigned short* bp = Bswz + ((size_t)(qq * 8) * 64 + lane) * 8;
#pragma unroll
            for (int nt = 0; nt < 8; ++nt) {
                short8 b = *reinterpret_cast<const short8*>(bp + (size_t)nt * 64 * 8);
                acc[0][nt] = __builtin_amdgcn_mfma_f32_16x16x32_bf16(a0, b, acc[0][nt], 0, 0, 0);
                acc[1][nt] = __builtin_amdgcn_mfma_f32_16x16x32_bf16(a1, b, acc[1][nt], 0, 0, 0);
            }
        }

#pragma unroll
        for (int nt = 0; nt < 8; ++nt) {
            const int col = nt * 16 + l15;
            const float bv = bias[col];
#pragma unroll
            for (int rt = 0; rt < 2; ++rt) {
#pragma unroll
                for (int i = 0; i < 4; ++i) {
                    int row = R0 + rt * 16 + quad * 4 + i;
                    if (row < n) {
                        float v = acc[rt][nt][i] + bv;
                        if (RELU) v = fmaxf(v, 0.f);
                        if (OUT_BF16) outb[(size_t)row * D + col] = f2bf(v);
                        else outf[(size_t)row * D + col] = v;
                    }
                }
            }
        }
    }
}

// ===========================================================================
// Fallback (atomic scatter + fp32 VALU GEMM) — only if ws is too small.
// ===========================================================================
__global__ void scatter_add_kernel(const float* __restrict__ x,
                                   const int* __restrict__ src,
                                   const int* __restrict__ dst,
                                   float* __restrict__ agg, int E) {
    int tid = blockIdx.x * blockDim.x + threadIdx.x;
    int e = tid >> 5;
    int lane = tid & 31;
    if (e >= E) return;
    int s = src[e];
    int d = dst[e];
    const float4 v = *reinterpret_cast<const float4*>(x + (size_t)s * D + lane * 4);
    float* a = agg + (size_t)d * D + lane * 4;
    unsafeAtomicAdd(a + 0, v.x);
    unsafeAtomicAdd(a + 1, v.y);
    unsafeAtomicAdd(a + 2, v.z);
    unsafeAtomicAdd(a + 3, v.w);
}

template <bool RELU>
__global__ __launch_bounds__(256) void dual_gemm_kernel(
    const float* __restrict__ agg, const float* __restrict__ hin,
    const float* __restrict__ Wrel, const float* __restrict__ brel,
    const float* __restrict__ Wroot, float* __restrict__ out, int n) {
    __shared__ float sA[32][D];
    __shared__ float sX[32][D];
    const int row0 = blockIdx.x * 32;
    const int t = threadIdx.x;
    for (int i = t; i < 32 * (D / 4); i += 256) {
        int r = i >> 5;
        int c = (i & 31) << 2;
        int row = row0 + r;
        float4 za = {0.f, 0.f, 0.f, 0.f};
        float4 zx = {0.f, 0.f, 0.f, 0.f};
        if (row < n) {
            za = *reinterpret_cast<const float4*>(agg + (size_t)row * D + c);
            zx = *reinterpret_cast<const float4*>(hin + (size_t)row * D + c);
        }
        *reinterpret_cast<float4*>(&sA[r][c]) = za;
        *reinterpret_cast<float4*>(&sX[r][c]) = zx;
    }
    __syncthreads();
    const int c4 = (t & 31) << 2;
    const int r0 = (t >> 5) << 2;
    float acc[4][4];
#pragma unroll
    for (int j = 0; j < 4; ++j)
#pragma unroll
        for (int c = 0; c < 4; ++c) acc[j][c] = 0.f;
    for (int k = 0; k < D; ++k) {
        const float4 wr = *reinterpret_cast<const float4*>(Wrel + k * D + c4);
        const float4 wo = *reinterpret_cast<const float4*>(Wroot + k * D + c4);
#pragma unroll
        for (int j = 0; j < 4; ++j) {
            const float a = sA[r0 + j][k];
            const float xv = sX[r0 + j][k];
            acc[j][0] = fmaf(a, wr.x, acc[j][0]);
            acc[j][1] = fmaf(a, wr.y, acc[j][1]);
            acc[j][2] = fmaf(a, wr.z, acc[j][2]);
            acc[j][3] = fmaf(a, wr.w, acc[j][3]);
            acc[j][0] = fmaf(xv, wo.x, acc[j][0]);
            acc[j][1] = fmaf(xv, wo.y, acc[j][1]);
            acc[j][2] = fmaf(xv, wo.z, acc[j][2]);
            acc[j][3] = fmaf(xv, wo.w, acc[j][3]);
        }
    }
    const float4 b = *reinterpret_cast<const float4*>(brel + c4);
#pragma unroll
    for (int j = 0; j < 4; ++j) {
        int row = row0 + r0 + j;
        if (row < n) {
            float4 v;
            v.x = acc[j][0] + b.x;
            v.y = acc[j][1] + b.y;
            v.z = acc[j][2] + b.z;
            v.w = acc[j][3] + b.w;
            if (RELU) {
                v.x = fmaxf(v.x, 0.f); v.y = fmaxf(v.y, 0.f);
                v.z = fmaxf(v.z, 0.f); v.w = fmaxf(v.w, 0.f);
            }
            *reinterpret_cast<float4*>(out + (size_t)row * D + c4) = v;
        }
    }
}

extern "C" void kernel_launch(void* const* d_in, const int* in_sizes, int n_in,
                              void* d_out, int out_size, void* d_ws,
                              size_t ws_size, hipStream_t stream) {
    const float* x       = (const float*)d_in[0];
    const int*   eidx    = (const int*)d_in[1];  // [2, E] flat: src then dst
    const float* W1_rel  = (const float*)d_in[2];
    const float* b1_rel  = (const float*)d_in[3];
    const float* W1_root = (const float*)d_in[4];
    const float* W2_rel  = (const float*)d_in[5];
    const float* b2_rel  = (const float*)d_in[6];
    const float* W2_root = (const float*)d_in[7];

    const int n = in_sizes[0] / D;  // 50000
    const int E = in_sizes[1] / 2;  // 625000
    const int* src = eidx;
    const int* dst = eidx + E;

    const size_t feat = (size_t)n * D;  // 6.4M elements

    // ws layout: xb | hb | aggb | bswz1 | bswz2 | cnt | esrc_padded
    const size_t need = feat * 2 * 3 + 65536 * 2 * 2 +
                        (size_t)n * sizeof(int) +
                        (size_t)n * CAP * sizeof(int);

    if (ws_size >= need) {
        unsigned short* xb    = (unsigned short*)d_ws;
        unsigned short* hb    = xb + feat;
        unsigned short* aggb  = hb + feat;
        unsigned short* bswz1 = aggb + feat;
        unsigned short* bswz2 = bswz1 + 8 * 8 * 64 * 8;  // 32768 ushorts
        int* cnt  = (int*)(bswz2 + 8 * 8 * 64 * 8);
        int* esrc = cnt + n;

        // 1) fused prep: zero counters + convert + both bswz
        prep_kernel<<<1024, 256, 0, stream>>>(
            x, W1_rel, W1_root, W2_rel, W2_root, xb, bswz1, bswz2, cnt,
            n, (int)(feat / 4));
        // 2) bucket-append adjacency build, 4 edges/thread
        const int build_blocks = ((E + 3) / 4 + 255) / 256;
        build_buckets_kernel<<<build_blocks, 256, 0, stream>>>(src, dst,
                                                               cnt, esrc, E);

        const int gth_blocks = (n * 16 + 255) / 256;
        const int gemm_blocks = (n + 127) / 128;

        // 3-4) Layer 1
        gather_bf16_kernel<<<gth_blocks, 256, 0, stream>>>(xb, cnt, esrc,
                                                           aggb, n);
        mfma_gemm_kernel<true, true><<<gemm_blocks, 256, 0, stream>>>(
            aggb, xb, bswz1, b1_rel, hb, nullptr, n);
        // 5-6) Layer 2
        gather_bf16_kernel<<<gth_blocks, 256, 0, stream>>>(hb, cnt, esrc,
                                                           aggb, n);
        mfma_gemm_kernel<false, false><<<gemm_blocks, 256, 0, stream>>>(
            aggb, hb, bswz2, b2_rel, nullptr, (float*)d_out, n);
    } else {
        // --- Fallback: atomic scatter + fp32 VALU GEMM ---
        float* agg = (float*)d_ws;
        float* h   = (float*)d_out;
        const size_t agg_bytes = feat * sizeof(float);
        const int sc_blocks = (E * 32 + 255) / 256;
        const int gemm_blocks = (n + 31) / 32;

        hipMemsetAsync(agg, 0, agg_bytes, stream);
        scatter_add_kernel<<<sc_blocks, 256, 0, stream>>>(x, src, dst, agg, E);
        dual_gemm_kernel<true><<<gemm_blocks, 256, 0, stream>>>(
            agg, x, W1_rel, b1_rel, W1_root, h, n);

        hipMemsetAsync(agg, 0, agg_bytes, stream);
        scatter_add_kernel<<<sc_blocks, 256, 0, stream>>>(h, src, dst, agg, E);
        dual_gemm_kernel<false><<<gemm_blocks, 256, 0, stream>>>(
            agg, h, W2_rel, b2_rel, W2_root, (float*)d_out, n);
    }
}

// Round 4
// 218.721 us; speedup vs baseline: 1.3165x; 1.3165x over previous
//
#include <hip/hip_runtime.h>

// Problem constants (from reference): N=50000, E=625000, D=128.
constexpr int D = 128;
constexpr int CAP = 64;   // per-node bucket capacity

using short8 = __attribute__((ext_vector_type(8))) short;
using f32x4  = __attribute__((ext_vector_type(4))) float;

// RNE float -> bf16 (finite inputs).
__device__ inline unsigned short f2bf(float f) {
    union { float f; unsigned u; } un;
    un.f = f;
    unsigned u = un.u;
    return (unsigned short)((u + 0x7fffu + ((u >> 16) & 1u)) >> 16);
}

// ===========================================================================
// Fused prep (1 dispatch): zero counters | fp32->bf16 x | both bswz blocks.
// (~5us measured R2: stayed under top-5 cutoff at x6 repeats.)
// ===========================================================================
__global__ __launch_bounds__(256) void prep_kernel(
    const float* __restrict__ x,
    const float* __restrict__ W1_rel, const float* __restrict__ W1_root,
    const float* __restrict__ W2_rel, const float* __restrict__ W2_root,
    unsigned short* __restrict__ xb,
    unsigned short* __restrict__ bswz1, unsigned short* __restrict__ bswz2,
    int* __restrict__ cnt, int n, int feat4) {
    const int gtid = blockIdx.x * blockDim.x + threadIdx.x;
    const int gsz = gridDim.x * blockDim.x;

    for (int i = gtid; i < n; i += gsz) cnt[i] = 0;  // ws is 0xAA-poisoned
    for (int i = gtid; i < feat4; i += gsz) {
        float4 v = reinterpret_cast<const float4*>(x)[i];
        unsigned short o[4] = {f2bf(v.x), f2bf(v.y), f2bf(v.z), f2bf(v.w)};
        reinterpret_cast<uint2*>(xb)[i] = *reinterpret_cast<uint2*>(o);
    }
    for (int idx = gtid; idx < 2 * 4096; idx += gsz) {
        const int which = idx >> 12;          // 0: layer1, 1: layer2
        const int id = idx & 4095;
        const int lane = id & 63;
        const int t = (id >> 6) & 7;
        const int qq = id >> 9;
        const float* W = (qq < 4) ? (which ? W2_rel : W1_rel)
                                  : (which ? W2_root : W1_root);
        const int col = t * 16 + (lane & 15);
        const int kbase = (qq & 3) * 32 + ((lane >> 4) * 8);
        unsigned short o[8];
#pragma unroll
        for (int j = 0; j < 8; ++j)
            o[j] = f2bf(W[(size_t)(kbase + j) * D + col]);
        uint4* dp = reinterpret_cast<uint4*>((which ? bswz2 : bswz1) +
                                             (size_t)id * 8);
        *dp = *reinterpret_cast<uint4*>(o);
    }
}

// ===========================================================================
// XCD-partitioned bucket build. R2 diagnosis: the old all-edges-anywhere
// append produced 625K x 64B line writebacks (37 MB, 46us) because a node's
// bucket line was dirtied from all 8 XCDs' L2s. Here cohort c (blockIdx&7,
// riding the round-robin XCD dispatch heuristic — perf-only, any mapping is
// still correct) scans ALL edges densely but appends only dst in its 1/8
// node range, so each bucket line is dirtied by a single XCD. Cost: 8x dense
// edge reads (40 MB, LLC-served after first touch) — far cheaper than the
// scattered writebacks it removes.
// ===========================================================================
__global__ __launch_bounds__(256) void build_buckets_xcd_kernel(
    const int* __restrict__ src, const int* __restrict__ dst,
    int* __restrict__ cnt, int* __restrict__ esrc, int E, int n) {
    const int cohort = blockIdx.x & 7;
    const int bpc = gridDim.x >> 3;        // blocks per cohort
    const int bi = blockIdx.x >> 3;        // block index within cohort
    const int span = (n + 7) >> 3;
    const int lo = cohort * span;
    const int hi = (lo + span < n) ? (lo + span) : n;
    const int nq = (E + 3) >> 2;           // edge quads

    for (int q = bi * blockDim.x + threadIdx.x; q < nq;
         q += bpc * blockDim.x) {
        const int base = q * 4;
        if (base + 3 < E) {
            const int4 s4 = *reinterpret_cast<const int4*>(src + base);
            const int4 d4 = *reinterpret_cast<const int4*>(dst + base);
            int p;
            if (d4.x >= lo && d4.x < hi) {
                p = atomicAdd(&cnt[d4.x], 1);
                if (p < CAP) esrc[d4.x * CAP + p] = s4.x;
            }
            if (d4.y >= lo && d4.y < hi) {
                p = atomicAdd(&cnt[d4.y], 1);
                if (p < CAP) esrc[d4.y * CAP + p] = s4.y;
            }
            if (d4.z >= lo && d4.z < hi) {
                p = atomicAdd(&cnt[d4.z], 1);
                if (p < CAP) esrc[d4.z * CAP + p] = s4.z;
            }
            if (d4.w >= lo && d4.w < hi) {
                p = atomicAdd(&cnt[d4.w], 1);
                if (p < CAP) esrc[d4.w * CAP + p] = s4.w;
            }
        } else {
            for (int i = base; i < E; ++i) {
                const int d = dst[i];
                if (d >= lo && d < hi) {
                    const int p = atomicAdd(&cnt[d], 1);
                    if (p < CAP) esrc[d * CAP + p] = src[i];
                }
            }
        }
    }
}

// ===========================================================================
// Fused gather + MFMA GEMM (one per layer): a block owns 128 output rows.
// Phase A: stage the block's X rows + gather-accumulate its agg rows into
// swizzled LDS tiles. Phase B: MFMA GEMM reading A-fragments from LDS.
// Swizzle: byte ^= ((row&7)<<4) on BOTH write (reg-staged) and read sides
// (rule #21 satisfied: no global_load_lds involved). Kills the agg global
// round-trip (12.8MB write + 12.8MB read per layer) and 2 dispatches.
// Cross-block input (xb/hb) is fully written by the PREVIOUS dispatch, so
// no inter-block dependency exists inside this kernel.
// ===========================================================================
__device__ inline void add8(float* acc, uint4 v) {
    const unsigned u0 = v.x, u1 = v.y, u2 = v.z, u3 = v.w;
    acc[0] += __uint_as_float(u0 << 16);
    acc[1] += __uint_as_float(u0 & 0xffff0000u);
    acc[2] += __uint_as_float(u1 << 16);
    acc[3] += __uint_as_float(u1 & 0xffff0000u);
    acc[4] += __uint_as_float(u2 << 16);
    acc[5] += __uint_as_float(u2 & 0xffff0000u);
    acc[6] += __uint_as_float(u3 << 16);
    acc[7] += __uint_as_float(u3 & 0xffff0000u);
}

template <bool RELU, bool OUT_BF16>
__global__ __launch_bounds__(256) void fused_gather_gemm_kernel(
    const unsigned short* __restrict__ xb,   // layer input bf16 [n][D]
    const int* __restrict__ cnt,
    const int* __restrict__ esrc,
    const unsigned short* __restrict__ Bswz,
    const float* __restrict__ bias,
    unsigned short* __restrict__ outb, float* __restrict__ outf, int n) {
    __shared__ unsigned short ldsA[128 * D];  // agg tile, swizzled (32 KB)
    __shared__ unsigned short ldsX[128 * D];  // root tile, swizzled (32 KB)

    const int t = threadIdx.x;
    const int R0 = blockIdx.x * 128;

    // ---- Phase A1: stage X tile (coalesced global read, swizzled LDS) ----
    {
        const int row0 = t >> 4;   // 0..15
        const int ch = t & 15;     // 16B chunk within row
        for (int r = row0; r < 128; r += 16) {
            int grow = R0 + r;
            grow = (grow < n) ? grow : (n - 1);  // clamped; stores predicated
            uint4 v = *reinterpret_cast<const uint4*>(
                xb + (size_t)grow * D + ch * 8);
            const int byte = (r * 256 + ch * 16) ^ ((r & 7) << 4);
            *reinterpret_cast<uint4*>(reinterpret_cast<char*>(ldsX) + byte) = v;
        }
    }

    // ---- Phase A2: gather agg rows (16-deep MLP body) into swizzled LDS ----
    {
        const int lane = t & 15;
        const int g0 = t >> 4;     // 0..15
        const size_t loff = (size_t)lane * 8;
        for (int gl = g0; gl < 128; gl += 16) {
            const int g = R0 + gl;
            float acc[8] = {0.f, 0.f, 0.f, 0.f, 0.f, 0.f, 0.f, 0.f};
            if (g < n) {
                int deg = cnt[g];
                deg = (deg < CAP) ? deg : CAP;
                const int beg = g * CAP;
                for (int j0 = 0; j0 < deg; j0 += 16) {
                    const int rem = deg - j0;
                    const int4 ia = *reinterpret_cast<const int4*>(esrc + beg + j0 + 0);
                    const int4 ib = *reinterpret_cast<const int4*>(esrc + beg + j0 + 4);
                    const int4 ic = *reinterpret_cast<const int4*>(esrc + beg + j0 + 8);
                    const int4 id = *reinterpret_cast<const int4*>(esrc + beg + j0 + 12);
                    const int s[16] = {ia.x, ia.y, ia.z, ia.w,
                                       ib.x, ib.y, ib.z, ib.w,
                                       ic.x, ic.y, ic.z, ic.w,
                                       id.x, id.y, id.z, id.w};
                    uint4 v[16];
#pragma unroll
                    for (int k = 0; k < 16; ++k) {
                        const int sk = (k < rem) ? s[k] : 0;
                        v[k] = *reinterpret_cast<const uint4*>(
                            xb + (size_t)sk * D + loff);
                    }
#pragma unroll
                    for (int k = 0; k < 16; ++k) {
                        if (k < rem) add8(acc, v[k]);
                    }
                }
            }
            unsigned short o[8];
#pragma unroll
            for (int i = 0; i < 8; ++i) o[i] = f2bf(acc[i]);
            const int byte = (gl * 256 + lane * 16) ^ ((gl & 7) << 4);
            *reinterpret_cast<uint4*>(reinterpret_cast<char*>(ldsA) + byte) =
                *reinterpret_cast<uint4*>(o);
        }
    }

    __syncthreads();

    // ---- Phase B: MFMA GEMM, A-fragments from swizzled LDS ----
    const int lane = t & 63;
    const int w = t >> 6;
    const int quad = lane >> 4;
    const int l15 = lane & 15;
    const int rA0 = w * 32 + l15;        // local row of fragment 0
    const int rA1 = w * 32 + 16 + l15;   // local row of fragment 1

    f32x4 acc[2][8];
#pragma unroll
    for (int rt = 0; rt < 2; ++rt)
#pragma unroll
        for (int nt = 0; nt < 8; ++nt)
            acc[rt][nt] = f32x4{0.f, 0.f, 0.f, 0.f};

#pragma unroll
    for (int qq = 0; qq < 8; ++qq) {
        const unsigned short* lsrc = (qq < 4) ? ldsA : ldsX;
        const int kbyte = (qq & 3) * 64 + quad * 16;  // byte offset in row
        const int b0 = (rA0 * 256 + kbyte) ^ ((rA0 & 7) << 4);
        const int b1 = (rA1 * 256 + kbyte) ^ ((rA1 & 7) << 4);
        short8 a0 = *reinterpret_cast<const short8*>(
            reinterpret_cast<const char*>(lsrc) + b0);
        short8 a1 = *reinterpret_cast<const short8*>(
            reinterpret_cast<const char*>(lsrc) + b1);
        const unsigned short* bp = Bswz + ((size_t)(qq * 8) * 64 + lane) * 8;
#pragma unroll
        for (int nt = 0; nt < 8; ++nt) {
            short8 b = *reinterpret_cast<const short8*>(bp + (size_t)nt * 64 * 8);
            acc[0][nt] = __builtin_amdgcn_mfma_f32_16x16x32_bf16(a0, b, acc[0][nt], 0, 0, 0);
            acc[1][nt] = __builtin_amdgcn_mfma_f32_16x16x32_bf16(a1, b, acc[1][nt], 0, 0, 0);
        }
    }

#pragma unroll
    for (int nt = 0; nt < 8; ++nt) {
        const int col = nt * 16 + l15;
        const float bv = bias[col];
#pragma unroll
        for (int rt = 0; rt < 2; ++rt) {
#pragma unroll
            for (int i = 0; i < 4; ++i) {
                const int row = R0 + w * 32 + rt * 16 + quad * 4 + i;
                if (row < n) {
                    float v = acc[rt][nt][i] + bv;
                    if (RELU) v = fmaxf(v, 0.f);
                    if (OUT_BF16) outb[(size_t)row * D + col] = f2bf(v);
                    else outf[(size_t)row * D + col] = v;
                }
            }
        }
    }
}

// ===========================================================================
// Fallback (atomic scatter + fp32 VALU GEMM) — only if ws is too small.
// ===========================================================================
__global__ void scatter_add_kernel(const float* __restrict__ x,
                                   const int* __restrict__ src,
                                   const int* __restrict__ dst,
                                   float* __restrict__ agg, int E) {
    int tid = blockIdx.x * blockDim.x + threadIdx.x;
    int e = tid >> 5;
    int lane = tid & 31;
    if (e >= E) return;
    int s = src[e];
    int d = dst[e];
    const float4 v = *reinterpret_cast<const float4*>(x + (size_t)s * D + lane * 4);
    float* a = agg + (size_t)d * D + lane * 4;
    unsafeAtomicAdd(a + 0, v.x);
    unsafeAtomicAdd(a + 1, v.y);
    unsafeAtomicAdd(a + 2, v.z);
    unsafeAtomicAdd(a + 3, v.w);
}

template <bool RELU>
__global__ __launch_bounds__(256) void dual_gemm_kernel(
    const float* __restrict__ agg, const float* __restrict__ hin,
    const float* __restrict__ Wrel, const float* __restrict__ brel,
    const float* __restrict__ Wroot, float* __restrict__ out, int n) {
    __shared__ float sA[32][D];
    __shared__ float sX[32][D];
    const int row0 = blockIdx.x * 32;
    const int t = threadIdx.x;
    for (int i = t; i < 32 * (D / 4); i += 256) {
        int r = i >> 5;
        int c = (i & 31) << 2;
        int row = row0 + r;
        float4 za = {0.f, 0.f, 0.f, 0.f};
        float4 zx = {0.f, 0.f, 0.f, 0.f};
        if (row < n) {
            za = *reinterpret_cast<const float4*>(agg + (size_t)row * D + c);
            zx = *reinterpret_cast<const float4*>(hin + (size_t)row * D + c);
        }
        *reinterpret_cast<float4*>(&sA[r][c]) = za;
        *reinterpret_cast<float4*>(&sX[r][c]) = zx;
    }
    __syncthreads();
    const int c4 = (t & 31) << 2;
    const int r0 = (t >> 5) << 2;
    float acc[4][4];
#pragma unroll
    for (int j = 0; j < 4; ++j)
#pragma unroll
        for (int c = 0; c < 4; ++c) acc[j][c] = 0.f;
    for (int k = 0; k < D; ++k) {
        const float4 wr = *reinterpret_cast<const float4*>(Wrel + k * D + c4);
        const float4 wo = *reinterpret_cast<const float4*>(Wroot + k * D + c4);
#pragma unroll
        for (int j = 0; j < 4; ++j) {
            const float a = sA[r0 + j][k];
            const float xv = sX[r0 + j][k];
            acc[j][0] = fmaf(a, wr.x, acc[j][0]);
            acc[j][1] = fmaf(a, wr.y, acc[j][1]);
            acc[j][2] = fmaf(a, wr.z, acc[j][2]);
            acc[j][3] = fmaf(a, wr.w, acc[j][3]);
            acc[j][0] = fmaf(xv, wo.x, acc[j][0]);
            acc[j][1] = fmaf(xv, wo.y, acc[j][1]);
            acc[j][2] = fmaf(xv, wo.z, acc[j][2]);
            acc[j][3] = fmaf(xv, wo.w, acc[j][3]);
        }
    }
    const float4 b = *reinterpret_cast<const float4*>(brel + c4);
#pragma unroll
    for (int j = 0; j < 4; ++j) {
        int row = row0 + r0 + j;
        if (row < n) {
            float4 v;
            v.x = acc[j][0] + b.x;
            v.y = acc[j][1] + b.y;
            v.z = acc[j][2] + b.z;
            v.w = acc[j][3] + b.w;
            if (RELU) {
                v.x = fmaxf(v.x, 0.f); v.y = fmaxf(v.y, 0.f);
                v.z = fmaxf(v.z, 0.f); v.w = fmaxf(v.w, 0.f);
            }
            *reinterpret_cast<float4*>(out + (size_t)row * D + c4) = v;
        }
    }
}

extern "C" void kernel_launch(void* const* d_in, const int* in_sizes, int n_in,
                              void* d_out, int out_size, void* d_ws,
                              size_t ws_size, hipStream_t stream) {
    const float* x       = (const float*)d_in[0];
    const int*   eidx    = (const int*)d_in[1];  // [2, E] flat: src then dst
    const float* W1_rel  = (const float*)d_in[2];
    const float* b1_rel  = (const float*)d_in[3];
    const float* W1_root = (const float*)d_in[4];
    const float* W2_rel  = (const float*)d_in[5];
    const float* b2_rel  = (const float*)d_in[6];
    const float* W2_root = (const float*)d_in[7];

    const int n = in_sizes[0] / D;  // 50000
    const int E = in_sizes[1] / 2;  // 625000
    const int* src = eidx;
    const int* dst = eidx + E;

    const size_t feat = (size_t)n * D;  // 6.4M elements

    // ws layout kept identical to previous rounds (aggb slot now unused):
    // xb | hb | (aggb, unused) | bswz1 | bswz2 | cnt | esrc_padded
    const size_t need = feat * 2 * 3 + 65536 * 2 * 2 +
                        (size_t)n * sizeof(int) +
                        (size_t)n * CAP * sizeof(int);

    if (ws_size >= need) {
        unsigned short* xb    = (unsigned short*)d_ws;
        unsigned short* hb    = xb + feat;
        unsigned short* aggb  = hb + feat;   // unused (kept for layout)
        unsigned short* bswz1 = aggb + feat;
        unsigned short* bswz2 = bswz1 + 8 * 8 * 64 * 8;  // 32768 ushorts
        int* cnt  = (int*)(bswz2 + 8 * 8 * 64 * 8);
        int* esrc = cnt + n;
        (void)aggb;

        // 1) fused prep: zero counters + convert + both bswz
        prep_kernel<<<1024, 256, 0, stream>>>(
            x, W1_rel, W1_root, W2_rel, W2_root, xb, bswz1, bswz2, cnt,
            n, (int)(feat / 4));
        // 2) XCD-partitioned bucket build: 128 blocks/cohort x 8 cohorts
        build_buckets_xcd_kernel<<<1024, 256, 0, stream>>>(src, dst, cnt,
                                                           esrc, E, n);

        const int fused_blocks = (n + 127) / 128;

        // 3) Layer 1: fused gather + GEMM (relu, bf16 out -> hb)
        fused_gather_gemm_kernel<true, true><<<fused_blocks, 256, 0, stream>>>(
            xb, cnt, esrc, bswz1, b1_rel, hb, nullptr, n);
        // 4) Layer 2: fused gather + GEMM (no relu, fp32 out -> d_out)
        fused_gather_gemm_kernel<false, false><<<fused_blocks, 256, 0, stream>>>(
            hb, cnt, esrc, bswz2, b2_rel, nullptr, (float*)d_out, n);
    } else {
        // --- Fallback: atomic scatter + fp32 VALU GEMM ---
        float* agg = (float*)d_ws;
        float* h   = (float*)d_out;
        const size_t agg_bytes = feat * sizeof(float);
        const int sc_blocks = (E * 32 + 255) / 256;
        const int gemm_blocks = (n + 31) / 32;

        hipMemsetAsync(agg, 0, agg_bytes, stream);
        scatter_add_kernel<<<sc_blocks, 256, 0, stream>>>(x, src, dst, agg, E);
        dual_gemm_kernel<true><<<gemm_blocks, 256, 0, stream>>>(
            agg, x, W1_rel, b1_rel, W1_root, h, n);

        hipMemsetAsync(agg, 0, agg_bytes, stream);
        scatter_add_kernel<<<sc_blocks, 256, 0, stream>>>(h, src, dst, agg, E);
        dual_gemm_kernel<false><<<gemm_blocks, 256, 0, stream>>>(
            agg, h, W2_rel, b2_rel, W2_root, (float*)d_out, n);
    }
}

// Round 5
// 209.427 us; speedup vs baseline: 1.3749x; 1.0444x over previous
//
#include <hip/hip_runtime.h>

// Problem constants (from reference): N=50000, E=625000, D=128.
constexpr int D = 128;
constexpr int CAP = 64;   // per-node bucket capacity

using short8 = __attribute__((ext_vector_type(8))) short;
using f32x4  = __attribute__((ext_vector_type(4))) float;

// RNE float -> bf16 (finite inputs).
__device__ inline unsigned short f2bf(float f) {
    union { float f; unsigned u; } un;
    un.f = f;
    unsigned u = un.u;
    return (unsigned short)((u + 0x7fffu + ((u >> 16) & 1u)) >> 16);
}

// ===========================================================================
// Fused prep (1 dispatch): zero counters | fp32->bf16 x | both bswz blocks.
// Measured ~5us (R2: stayed under top-5 cutoff at x6 repeats).
// ===========================================================================
__global__ __launch_bounds__(256) void prep_kernel(
    const float* __restrict__ x,
    const float* __restrict__ W1_rel, const float* __restrict__ W1_root,
    const float* __restrict__ W2_rel, const float* __restrict__ W2_root,
    unsigned short* __restrict__ xb,
    unsigned short* __restrict__ bswz1, unsigned short* __restrict__ bswz2,
    int* __restrict__ cnt, int n, int feat4) {
    const int gtid = blockIdx.x * blockDim.x + threadIdx.x;
    const int gsz = gridDim.x * blockDim.x;

    for (int i = gtid; i < n; i += gsz) cnt[i] = 0;  // ws is 0xAA-poisoned
    for (int i = gtid; i < feat4; i += gsz) {
        float4 v = reinterpret_cast<const float4*>(x)[i];
        unsigned short o[4] = {f2bf(v.x), f2bf(v.y), f2bf(v.z), f2bf(v.w)};
        reinterpret_cast<uint2*>(xb)[i] = *reinterpret_cast<uint2*>(o);
    }
    for (int idx = gtid; idx < 2 * 4096; idx += gsz) {
        const int which = idx >> 12;          // 0: layer1, 1: layer2
        const int id = idx & 4095;
        const int lane = id & 63;
        const int t = (id >> 6) & 7;
        const int qq = id >> 9;
        const float* W = (qq < 4) ? (which ? W2_rel : W1_rel)
                                  : (which ? W2_root : W1_root);
        const int col = t * 16 + (lane & 15);
        const int kbase = (qq & 3) * 32 + ((lane >> 4) * 8);
        unsigned short o[8];
#pragma unroll
        for (int j = 0; j < 8; ++j)
            o[j] = f2bf(W[(size_t)(kbase + j) * D + col]);
        uint4* dp = reinterpret_cast<uint4*>((which ? bswz2 : bswz1) +
                                             (size_t)id * 8);
        *dp = *reinterpret_cast<uint4*>(o);
    }
}

// ===========================================================================
// XCD-partitioned bucket build. R2 diagnosis: all-edges-anywhere append
// produced 625K x 64B scattered line writebacks (37 MB WRITE_SIZE, 46us,
// VALUBusy 0.26%) because each node's bucket line was dirtied from all 8
// XCDs' L2s. Cohort c = blockIdx&7 (rides the round-robin XCD dispatch
// heuristic — perf-only, correctness holds under any mapping) scans ALL
// edges densely but appends only dst in its 1/8 node range. Per-cohort
// bucket region = 6250 nodes x 256B = 1.6 MB -> fits a single XCD's 4 MB
// L2, so writeback ~= unique dirty lines (~3 MB total) instead of 40 MB.
// Cost: 8x dense edge reads (40 MB, L3-served) ~ 7us of BW.
// ===========================================================================
__global__ __launch_bounds__(256) void build_buckets_xcd_kernel(
    const int* __restrict__ src, const int* __restrict__ dst,
    int* __restrict__ cnt, int* __restrict__ esrc, int E, int n) {
    const int cohort = blockIdx.x & 7;
    const int bpc = gridDim.x >> 3;        // blocks per cohort
    const int bi = blockIdx.x >> 3;        // block index within cohort
    const int span = (n + 7) >> 3;
    const int lo = cohort * span;
    const int hi = (lo + span < n) ? (lo + span) : n;
    const int nq = (E + 3) >> 2;           // edge quads

    for (int q = bi * blockDim.x + threadIdx.x; q < nq;
         q += bpc * blockDim.x) {
        const int base = q * 4;
        if (base + 3 < E) {
            const int4 s4 = *reinterpret_cast<const int4*>(src + base);
            const int4 d4 = *reinterpret_cast<const int4*>(dst + base);
            int p;
            if (d4.x >= lo && d4.x < hi) {
                p = atomicAdd(&cnt[d4.x], 1);
                if (p < CAP) esrc[d4.x * CAP + p] = s4.x;
            }
            if (d4.y >= lo && d4.y < hi) {
                p = atomicAdd(&cnt[d4.y], 1);
                if (p < CAP) esrc[d4.y * CAP + p] = s4.y;
            }
            if (d4.z >= lo && d4.z < hi) {
                p = atomicAdd(&cnt[d4.z], 1);
                if (p < CAP) esrc[d4.z * CAP + p] = s4.z;
            }
            if (d4.w >= lo && d4.w < hi) {
                p = atomicAdd(&cnt[d4.w], 1);
                if (p < CAP) esrc[d4.w * CAP + p] = s4.w;
            }
        } else {
            for (int i = base; i < E; ++i) {
                const int d = dst[i];
                if (d >= lo && d < hi) {
                    const int p = atomicAdd(&cnt[d], 1);
                    if (p < CAP) esrc[d * CAP + p] = src[i];
                }
            }
        }
    }
}

// ===========================================================================
// bf16 gather-accumulate, 16-deep MLP version (~15us measured, R1 ablation).
// STANDALONE again — R3 proved fusing it into the GEMM block collapses
// occupancy (2 blocks/CU from 64KB LDS) and costs +30us/layer.
// ===========================================================================
__device__ inline void add8(float* acc, uint4 v) {
    const unsigned u0 = v.x, u1 = v.y, u2 = v.z, u3 = v.w;
    acc[0] += __uint_as_float(u0 << 16);
    acc[1] += __uint_as_float(u0 & 0xffff0000u);
    acc[2] += __uint_as_float(u1 << 16);
    acc[3] += __uint_as_float(u1 & 0xffff0000u);
    acc[4] += __uint_as_float(u2 << 16);
    acc[5] += __uint_as_float(u2 & 0xffff0000u);
    acc[6] += __uint_as_float(u3 << 16);
    acc[7] += __uint_as_float(u3 & 0xffff0000u);
}

__global__ __launch_bounds__(256) void gather_bf16_kernel(
    const unsigned short* __restrict__ xb,
    const int* __restrict__ cnt,
    const int* __restrict__ esrc,
    unsigned short* __restrict__ aggb, int n) {
    const int tid = blockIdx.x * blockDim.x + threadIdx.x;
    const int g = tid >> 4;
    const int lane = tid & 15;
    if (g >= n) return;
    int deg = cnt[g];
    deg = (deg < CAP) ? deg : CAP;
    const int beg = g * CAP;
    const size_t loff = (size_t)lane * 8;
    float acc[8] = {0.f, 0.f, 0.f, 0.f, 0.f, 0.f, 0.f, 0.f};

    for (int j0 = 0; j0 < deg; j0 += 16) {
        const int rem = deg - j0;
        const int4 ia = *reinterpret_cast<const int4*>(esrc + beg + j0 + 0);
        const int4 ib = *reinterpret_cast<const int4*>(esrc + beg + j0 + 4);
        const int4 ic = *reinterpret_cast<const int4*>(esrc + beg + j0 + 8);
        const int4 id = *reinterpret_cast<const int4*>(esrc + beg + j0 + 12);
        const int s[16] = {ia.x, ia.y, ia.z, ia.w, ib.x, ib.y, ib.z, ib.w,
                           ic.x, ic.y, ic.z, ic.w, id.x, id.y, id.z, id.w};
        uint4 v[16];
#pragma unroll
        for (int k = 0; k < 16; ++k) {
            const int sk = (k < rem) ? s[k] : 0;
            v[k] = *reinterpret_cast<const uint4*>(xb + (size_t)sk * D + loff);
        }
#pragma unroll
        for (int k = 0; k < 16; ++k) {
            if (k < rem) add8(acc, v[k]);
        }
    }

    unsigned short o[8];
#pragma unroll
    for (int i = 0; i < 8; ++i) o[i] = f2bf(acc[i]);
    *reinterpret_cast<uint4*>(aggb + (size_t)g * D + lane * 8) =
        *reinterpret_cast<uint4*>(o);
}

// ===========================================================================
// MFMA GEMM: out[i,:] = (relu?)( Ab[i,:] @ Wrel + bias + Xb[i,:] @ Wroot )
// K = 256, bf16 inputs, fp32 acc. Block = 4 waves; wave = 32 rows x 128 cols.
// No LDS, no barriers. ~7.6us measured (R2, x7 repeats).
// ===========================================================================
template <bool RELU, bool OUT_BF16>
__global__ __launch_bounds__(256) void mfma_gemm_kernel(
    const unsigned short* __restrict__ Ab, const unsigned short* __restrict__ Xb,
    const unsigned short* __restrict__ Bswz, const float* __restrict__ bias,
    unsigned short* __restrict__ outb, float* __restrict__ outf, int n) {
    const int t = threadIdx.x;
    const int lane = t & 63;
    const int w = t >> 6;
    const int quad = lane >> 4;
    const int l15 = lane & 15;
    const int R0 = blockIdx.x * 128 + w * 32;

    f32x4 acc[2][8];
#pragma unroll
    for (int rt = 0; rt < 2; ++rt)
#pragma unroll
        for (int nt = 0; nt < 8; ++nt)
            acc[rt][nt] = f32x4{0.f, 0.f, 0.f, 0.f};

    int rowA0 = R0 + l15;
    int rowA1 = R0 + 16 + l15;
    rowA0 = (rowA0 < n) ? rowA0 : (n - 1);
    rowA1 = (rowA1 < n) ? rowA1 : (n - 1);

    for (int qq = 0; qq < 8; ++qq) {
        const unsigned short* Asrc = (qq < 4) ? Ab : Xb;
        const int kb = (qq & 3) * 32 + quad * 8;
        short8 a0 = *reinterpret_cast<const short8*>(Asrc + (size_t)rowA0 * D + kb);
        short8 a1 = *reinterpret_cast<const short8*>(Asrc + (size_t)rowA1 * D + kb);
        const unsigned short* bp = Bswz + ((size_t)(qq * 8) * 64 + lane) * 8;
#pragma unroll
        for (int nt = 0; nt < 8; ++nt) {
            short8 b = *reinterpret_cast<const short8*>(bp + (size_t)nt * 64 * 8);
            acc[0][nt] = __builtin_amdgcn_mfma_f32_16x16x32_bf16(a0, b, acc[0][nt], 0, 0, 0);
            acc[1][nt] = __builtin_amdgcn_mfma_f32_16x16x32_bf16(a1, b, acc[1][nt], 0, 0, 0);
        }
    }

#pragma unroll
    for (int nt = 0; nt < 8; ++nt) {
        const int col = nt * 16 + l15;
        const float bv = bias[col];
#pragma unroll
        for (int rt = 0; rt < 2; ++rt) {
#pragma unroll
            for (int i = 0; i < 4; ++i) {
                int row = R0 + rt * 16 + quad * 4 + i;
                if (row < n) {
                    float v = acc[rt][nt][i] + bv;
                    if (RELU) v = fmaxf(v, 0.f);
                    if (OUT_BF16) outb[(size_t)row * D + col] = f2bf(v);
                    else outf[(size_t)row * D + col] = v;
                }
            }
        }
    }
}

// ===========================================================================
// Fallback (atomic scatter + fp32 VALU GEMM) — only if ws is too small.
// ===========================================================================
__global__ void scatter_add_kernel(const float* __restrict__ x,
                                   const int* __restrict__ src,
                                   const int* __restrict__ dst,
                                   float* __restrict__ agg, int E) {
    int tid = blockIdx.x * blockDim.x + threadIdx.x;
    int e = tid >> 5;
    int lane = tid & 31;
    if (e >= E) return;
    int s = src[e];
    int d = dst[e];
    const float4 v = *reinterpret_cast<const float4*>(x + (size_t)s * D + lane * 4);
    float* a = agg + (size_t)d * D + lane * 4;
    unsafeAtomicAdd(a + 0, v.x);
    unsafeAtomicAdd(a + 1, v.y);
    unsafeAtomicAdd(a + 2, v.z);
    unsafeAtomicAdd(a + 3, v.w);
}

template <bool RELU>
__global__ __launch_bounds__(256) void dual_gemm_kernel(
    const float* __restrict__ agg, const float* __restrict__ hin,
    const float* __restrict__ Wrel, const float* __restrict__ brel,
    const float* __restrict__ Wroot, float* __restrict__ out, int n) {
    __shared__ float sA[32][D];
    __shared__ float sX[32][D];
    const int row0 = blockIdx.x * 32;
    const int t = threadIdx.x;
    for (int i = t; i < 32 * (D / 4); i += 256) {
        int r = i >> 5;
        int c = (i & 31) << 2;
        int row = row0 + r;
        float4 za = {0.f, 0.f, 0.f, 0.f};
        float4 zx = {0.f, 0.f, 0.f, 0.f};
        if (row < n) {
            za = *reinterpret_cast<const float4*>(agg + (size_t)row * D + c);
            zx = *reinterpret_cast<const float4*>(hin + (size_t)row * D + c);
        }
        *reinterpret_cast<float4*>(&sA[r][c]) = za;
        *reinterpret_cast<float4*>(&sX[r][c]) = zx;
    }
    __syncthreads();
    const int c4 = (t & 31) << 2;
    const int r0 = (t >> 5) << 2;
    float acc[4][4];
#pragma unroll
    for (int j = 0; j < 4; ++j)
#pragma unroll
        for (int c = 0; c < 4; ++c) acc[j][c] = 0.f;
    for (int k = 0; k < D; ++k) {
        const float4 wr = *reinterpret_cast<const float4*>(Wrel + k * D + c4);
        const float4 wo = *reinterpret_cast<const float4*>(Wroot + k * D + c4);
#pragma unroll
        for (int j = 0; j < 4; ++j) {
            const float a = sA[r0 + j][k];
            const float xv = sX[r0 + j][k];
            acc[j][0] = fmaf(a, wr.x, acc[j][0]);
            acc[j][1] = fmaf(a, wr.y, acc[j][1]);
            acc[j][2] = fmaf(a, wr.z, acc[j][2]);
            acc[j][3] = fmaf(a, wr.w, acc[j][3]);
            acc[j][0] = fmaf(xv, wo.x, acc[j][0]);
            acc[j][1] = fmaf(xv, wo.y, acc[j][1]);
            acc[j][2] = fmaf(xv, wo.z, acc[j][2]);
            acc[j][3] = fmaf(xv, wo.w, acc[j][3]);
        }
    }
    const float4 b = *reinterpret_cast<const float4*>(brel + c4);
#pragma unroll
    for (int j = 0; j < 4; ++j) {
        int row = row0 + r0 + j;
        if (row < n) {
            float4 v;
            v.x = acc[j][0] + b.x;
            v.y = acc[j][1] + b.y;
            v.z = acc[j][2] + b.z;
            v.w = acc[j][3] + b.w;
            if (RELU) {
                v.x = fmaxf(v.x, 0.f); v.y = fmaxf(v.y, 0.f);
                v.z = fmaxf(v.z, 0.f); v.w = fmaxf(v.w, 0.f);
            }
            *reinterpret_cast<float4*>(out + (size_t)row * D + c4) = v;
        }
    }
}

extern "C" void kernel_launch(void* const* d_in, const int* in_sizes, int n_in,
                              void* d_out, int out_size, void* d_ws,
                              size_t ws_size, hipStream_t stream) {
    const float* x       = (const float*)d_in[0];
    const int*   eidx    = (const int*)d_in[1];  // [2, E] flat: src then dst
    const float* W1_rel  = (const float*)d_in[2];
    const float* b1_rel  = (const float*)d_in[3];
    const float* W1_root = (const float*)d_in[4];
    const float* W2_rel  = (const float*)d_in[5];
    const float* b2_rel  = (const float*)d_in[6];
    const float* W2_root = (const float*)d_in[7];

    const int n = in_sizes[0] / D;  // 50000
    const int E = in_sizes[1] / 2;  // 625000
    const int* src = eidx;
    const int* dst = eidx + E;

    const size_t feat = (size_t)n * D;  // 6.4M elements

    // ws layout: xb | hb | aggb | bswz1 | bswz2 | cnt | esrc_padded
    const size_t need = feat * 2 * 3 + 65536 * 2 * 2 +
                        (size_t)n * sizeof(int) +
                        (size_t)n * CAP * sizeof(int);

    if (ws_size >= need) {
        unsigned short* xb    = (unsigned short*)d_ws;
        unsigned short* hb    = xb + feat;
        unsigned short* aggb  = hb + feat;
        unsigned short* bswz1 = aggb + feat;
        unsigned short* bswz2 = bswz1 + 8 * 8 * 64 * 8;  // 32768 ushorts
        int* cnt  = (int*)(bswz2 + 8 * 8 * 64 * 8);
        int* esrc = cnt + n;

        // 1) fused prep: zero counters + convert + both bswz
        prep_kernel<<<1024, 256, 0, stream>>>(
            x, W1_rel, W1_root, W2_rel, W2_root, xb, bswz1, bswz2, cnt,
            n, (int)(feat / 4));
        // 2) XCD-partitioned bucket build: 128 blocks/cohort x 8 cohorts
        build_buckets_xcd_kernel<<<1024, 256, 0, stream>>>(src, dst, cnt,
                                                           esrc, E, n);

        const int gth_blocks = (n * 16 + 255) / 256;
        const int gemm_blocks = (n + 127) / 128;

        // 3-4) Layer 1
        gather_bf16_kernel<<<gth_blocks, 256, 0, stream>>>(xb, cnt, esrc,
                                                           aggb, n);
        mfma_gemm_kernel<true, true><<<gemm_blocks, 256, 0, stream>>>(
            aggb, xb, bswz1, b1_rel, hb, nullptr, n);
        // 5-6) Layer 2
        gather_bf16_kernel<<<gth_blocks, 256, 0, stream>>>(hb, cnt, esrc,
                                                           aggb, n);
        mfma_gemm_kernel<false, false><<<gemm_blocks, 256, 0, stream>>>(
            aggb, hb, bswz2, b2_rel, nullptr, (float*)d_out, n);
    } else {
        // --- Fallback: atomic scatter + fp32 VALU GEMM ---
        float* agg = (float*)d_ws;
        float* h   = (float*)d_out;
        const size_t agg_bytes = feat * sizeof(float);
        const int sc_blocks = (E * 32 + 255) / 256;
        const int gemm_blocks = (n + 31) / 32;

        hipMemsetAsync(agg, 0, agg_bytes, stream);
        scatter_add_kernel<<<sc_blocks, 256, 0, stream>>>(x, src, dst, agg, E);
        dual_gemm_kernel<true><<<gemm_blocks, 256, 0, stream>>>(
            agg, x, W1_rel, b1_rel, W1_root, h, n);

        hipMemsetAsync(agg, 0, agg_bytes, stream);
        scatter_add_kernel<<<sc_blocks, 256, 0, stream>>>(h, src, dst, agg, E);
        dual_gemm_kernel<false><<<gemm_blocks, 256, 0, stream>>>(
            agg, h, W2_rel, b2_rel, W2_root, (float*)d_out, n);
    }
}